// Round 3
// baseline (676.173 us; speedup 1.0000x reference)
//
#include <hip/hip_runtime.h>
#include <stdint.h>

typedef unsigned long long u64;
typedef unsigned int u32;
typedef unsigned short u16;

// Fixed problem shape (N=100000, E=1600000, C_IN=C_OUT=128, NHEADS=4)
#define CIN 128
#define NN 100000
#define EE 1600000

__device__ __forceinline__ double bf2d(u16 v) {
    union { u32 u; float f; } cv;
    cv.u = ((u32)v) << 16;           // bf16 -> f32 upcast is a shift (exact)
    return (double)cv.f;             // f32 -> f64 exact
}

// Monotonic map: double -> u64 preserving total order (for atomicMax)
__device__ __forceinline__ u64 mono(double d) {
    long long l = __double_as_longlong(d);
    return (l >= 0) ? (((u64)l) | 0x8000000000000000ULL) : ~((u64)l);
}

// ---------------------------------------------------------------------------
// Init: zero x_out region of d_out (f32!), zero segmax, argmin sentinel, nm=0
__global__ void k_init(uint4* __restrict__ xout16, int n_xout16,
                       u64* __restrict__ segmax, int* __restrict__ argmin, int nh4,
                       int* __restrict__ nm, int n_nodes) {
    int stride = gridDim.x * blockDim.x;
    int tid = blockIdx.x * blockDim.x + threadIdx.x;
    uint4 z; z.x = 0; z.y = 0; z.z = 0; z.w = 0;
    for (int i = tid; i < n_xout16; i += stride) xout16[i] = z;
    for (int i = tid; i < nh4; i += stride) { segmax[i] = 0ULL; argmin[i] = 0x7FFFFFFF; }
    for (int i = tid; i < n_nodes; i += stride) nm[i] = 0;
}

// ---------------------------------------------------------------------------
// V[k*8 + h8] = sum_c weight[k, head*32+c] * att[0, head, off+c]
// h8 in [0,4): w_j (off=0); h8 in [4,8): w_i (off=32)
__global__ void k_prep_v(const u16* __restrict__ W, const u16* __restrict__ att,
                         double* __restrict__ V) {
    int t = blockIdx.x * blockDim.x + threadIdx.x;
    if (t >= 1024) return;
    int k = t >> 3, h8 = t & 7;
    int head = h8 & 3;
    int off = (h8 < 4) ? 0 : 32;
    double acc = 0.0;
    #pragma unroll
    for (int c = 0; c < 32; ++c)
        acc += bf2d(W[k * CIN + head * 32 + c]) * bf2d(att[head * 64 + off + c]);
    V[t] = acc;
}

// ---------------------------------------------------------------------------
// s[n][0..3] = s_j heads, s[n][4..7] = s_i heads;  s = x @ V  (exact f64)
__global__ __launch_bounds__(256) void k_s(const u16* __restrict__ x,
                                           const double* __restrict__ V,
                                           double* __restrict__ s, int n_nodes) {
    __shared__ double Vl[1024];
    for (int i = threadIdx.x; i < 1024; i += 256) Vl[i] = V[i];
    __syncthreads();
    int n = blockIdx.x * blockDim.x + threadIdx.x;
    if (n >= n_nodes) return;
    const uint4* row = (const uint4*)(x + (size_t)n * CIN);
    double acc[8];
    #pragma unroll
    for (int h = 0; h < 8; ++h) acc[h] = 0.0;
    #pragma unroll
    for (int q = 0; q < 16; ++q) {
        uint4 v = row[q];
        u32 w[4] = { v.x, v.y, v.z, v.w };
        #pragma unroll
        for (int j = 0; j < 4; ++j) {
            double x0 = bf2d((u16)(w[j] & 0xFFFFu));
            double x1 = bf2d((u16)(w[j] >> 16));
            int k0 = q * 8 + j * 2;
            #pragma unroll
            for (int h = 0; h < 8; ++h) acc[h] += x0 * Vl[k0 * 8 + h];
            #pragma unroll
            for (int h = 0; h < 8; ++h) acc[h] += x1 * Vl[(k0 + 1) * 8 + h];
        }
    }
    double* so = s + (size_t)n * 8;
    #pragma unroll
    for (int h = 0; h < 8; ++h) so[h] = acc[h];
}

// ---------------------------------------------------------------------------
// Pass 1 over edges: segmax[src,h] = max(alpha)
__global__ __launch_bounds__(256) void k_segmax(const int* __restrict__ ei,
                                                const double* __restrict__ s,
                                                u64* __restrict__ segmax, int n_edges) {
    int e = blockIdx.x * blockDim.x + threadIdx.x;
    if (e >= n_edges) return;
    int src = ei[e], dst = ei[n_edges + e];
    const double* sj = s + (size_t)src * 8;
    const double* si = s + (size_t)dst * 8 + 4;
    #pragma unroll
    for (int h = 0; h < 4; ++h) {
        u64 key = mono(sj[h] + si[h]);
        atomicMax(&segmax[src * 4 + h], key);
    }
}

// ---------------------------------------------------------------------------
// Pass 2 over edges: among alpha == segmax, take min edge id
__global__ __launch_bounds__(256) void k_argmin(const int* __restrict__ ei,
                                                const double* __restrict__ s,
                                                const u64* __restrict__ segmax,
                                                int* __restrict__ argmin, int n_edges) {
    int e = blockIdx.x * blockDim.x + threadIdx.x;
    if (e >= n_edges) return;
    int src = ei[e], dst = ei[n_edges + e];
    const double* sj = s + (size_t)src * 8;
    const double* si = s + (size_t)dst * 8 + 4;
    #pragma unroll
    for (int h = 0; h < 4; ++h) {
        u64 key = mono(sj[h] + si[h]);   // identical bits to pass 1 (same loads, one add)
        if (key == segmax[src * 4 + h]) atomicMin(&argmin[src * 4 + h], e);
    }
}

// ---------------------------------------------------------------------------
// Per (node,head): selected edge -> node_mask[dst] = 1
__global__ void k_nodemask(const int* __restrict__ ei, const int* __restrict__ argmin,
                           int* __restrict__ nm, int n_nodes, int n_edges) {
    int t = blockIdx.x * blockDim.x + threadIdx.x;
    if (t >= n_nodes * 4) return;
    int e = argmin[t];
    if (e < n_edges) nm[ei[n_edges + e]] = 1;
}

// ---------------------------------------------------------------------------
// edge_keep[e] = nm[src] & nm[dst], written as f32 1.0/0.0, 4 edges/thread
__global__ void k_edgekeep(const int* __restrict__ ei, const int* __restrict__ nm,
                           float4* __restrict__ out_ek, int n_edges) {
    int t = blockIdx.x * blockDim.x + threadIdx.x;
    int e0 = 4 * t;
    if (e0 >= n_edges) return;
    float4 v;
    v.x = (nm[ei[e0 + 0]] & nm[ei[n_edges + e0 + 0]]) ? 1.0f : 0.0f;
    v.y = (nm[ei[e0 + 1]] & nm[ei[n_edges + e0 + 1]]) ? 1.0f : 0.0f;
    v.z = (nm[ei[e0 + 2]] & nm[ei[n_edges + e0 + 2]]) ? 1.0f : 0.0f;
    v.w = (nm[ei[e0 + 3]] & nm[ei[n_edges + e0 + 3]]) ? 1.0f : 0.0f;
    out_ek[t] = v;
}

// ---------------------------------------------------------------------------
// node_mask f32 out + batch_slices f32 out
__global__ void k_nm_out(const int* __restrict__ nm, const int* __restrict__ slices,
                         float* __restrict__ out, int n_nodes, int nm_off, int sl_off) {
    int n = blockIdx.x * blockDim.x + threadIdx.x;
    if (n < n_nodes) out[nm_off + n] = nm[n] ? 1.0f : 0.0f;
    if (n < 2) out[sl_off + n] = (float)slices[n];   // 0 and 100000, both exact in f32
}

// ---------------------------------------------------------------------------
extern "C" void kernel_launch(void* const* d_in, const int* in_sizes, int n_in,
                              void* d_out, int out_size, void* d_ws, size_t ws_size,
                              hipStream_t stream) {
    // Bind inputs by UNIQUE flat size (permutation-proof; sizes are distinct):
    //   x: 12,800,000 bf16 | edge_index: 3,200,000 i32 | slices: 2 i32
    //   weight: 16,384 bf16 | att: 256 bf16
    const u16* x = nullptr; const int* ei = nullptr; const int* sl = nullptr;
    const u16* W = nullptr; const u16* att = nullptr;
    for (int i = 0; i < n_in; ++i) {
        switch (in_sizes[i]) {
            case NN * CIN:   x   = (const u16*)d_in[i]; break;
            case 2 * EE:     ei  = (const int*)d_in[i]; break;
            case 2:          sl  = (const int*)d_in[i]; break;
            case CIN * CIN:  W   = (const u16*)d_in[i]; break;
            case 256:        att = (const u16*)d_in[i]; break;
            default: break;
        }
    }
    if (!x || !ei || !sl || !W || !att) return;

    float* out = (float*)d_out;             // f32 concat, return order
    const int N = NN;
    const int E = EE;

    // output layout (f32 elements): [x_out N*128][edge_keep E][node_mask N][slices 2]
    const int ek_off = N * CIN;
    const int nm_off = ek_off + E;
    const int sl_off = nm_off + N;

    // workspace layout (bytes, all 16B aligned) — total ~11.1 MiB
    char* ws = (char*)d_ws;
    double* V    = (double*)(ws);                                  // 8 KB
    double* s    = (double*)(ws + 8192);                           // N*64 B
    u64*  segmax = (u64*) (ws + 8192 + (size_t)N * 64);            // N*32 B
    int*  argmin = (int*) (ws + 8192 + (size_t)N * 64 + (size_t)N * 32);
    int*  nm     = (int*) (ws + 8192 + (size_t)N * 64 + (size_t)N * 32 + (size_t)N * 16);

    const int n_xout16 = N * CIN / 4;     // uint4 count for f32 x_out zero region

    k_init<<<1024, 256, 0, stream>>>((uint4*)out, n_xout16, segmax, argmin, N * 4, nm, N);
    k_prep_v<<<4, 256, 0, stream>>>(W, att, V);
    k_s<<<(N + 255) / 256, 256, 0, stream>>>(x, V, s, N);
    k_segmax<<<(E + 255) / 256, 256, 0, stream>>>(ei, s, segmax, E);
    k_argmin<<<(E + 255) / 256, 256, 0, stream>>>(ei, s, segmax, argmin, E);
    k_nodemask<<<(N * 4 + 255) / 256, 256, 0, stream>>>(ei, argmin, nm, N, E);
    k_edgekeep<<<(E / 4 + 255) / 256, 256, 0, stream>>>(ei, nm, (float4*)(out + ek_off), E);
    k_nm_out<<<(N + 255) / 256, 256, 0, stream>>>(nm, sl, out, N, nm_off, sl_off);
}

// Round 4
// 411.016 us; speedup vs baseline: 1.6451x; 1.6451x over previous
//
#include <hip/hip_runtime.h>
#include <stdint.h>

typedef unsigned long long u64;
typedef unsigned int u32;
typedef unsigned short u16;

// Fixed problem shape (N=100000, E=1600000, C_IN=C_OUT=128, NHEADS=4)
#define CIN 128
#define NN 100000
#define EE 1600000

__device__ __forceinline__ double bf2d(u16 v) {
    union { u32 u; float f; } cv;
    cv.u = ((u32)v) << 16;           // bf16 -> f32 upcast is a shift (exact)
    return (double)cv.f;             // f32 -> f64 exact
}

// Monotonic map: f32 -> u32 preserving total order (for packed atomicMax key)
__device__ __forceinline__ u32 mono32(float f) {
    u32 u = __float_as_uint(f);
    return ((int)u >= 0) ? (u | 0x80000000u) : ~u;
}

// Hardware XCD id (0..7 on MI355X) — measured working on gfx950 (learn_hip m09).
// Used ONLY as a locality hint for per-XCD atomic tables; correctness does not
// depend on the mapping.
__device__ __forceinline__ u32 xcd_id() {
    u32 x;
    asm volatile("s_getreg_b32 %0, hwreg(HW_REG_XCC_ID)" : "=s"(x));
    return x & 7u;
}

// ---------------------------------------------------------------------------
// Init: zero x_out region of d_out (f32), zero seg tables (P copies), nm=0
__global__ void k_init(uint4* __restrict__ xout16, int n_xout16,
                       uint4* __restrict__ seg16, int n_seg16,
                       int* __restrict__ nm, int n_nodes) {
    int stride = gridDim.x * blockDim.x;
    int tid = blockIdx.x * blockDim.x + threadIdx.x;
    uint4 z; z.x = 0; z.y = 0; z.z = 0; z.w = 0;
    for (int i = tid; i < n_xout16; i += stride) xout16[i] = z;
    for (int i = tid; i < n_seg16; i += stride) seg16[i] = z;
    for (int i = tid; i < n_nodes; i += stride) nm[i] = 0;
}

// ---------------------------------------------------------------------------
// V[k*8 + h8] = sum_c weight[k, head*32+c] * att[0, head, off+c]   (f64 exact)
__global__ void k_prep_v(const u16* __restrict__ W, const u16* __restrict__ att,
                         double* __restrict__ V) {
    int t = blockIdx.x * blockDim.x + threadIdx.x;
    if (t >= 1024) return;
    int k = t >> 3, h8 = t & 7;
    int head = h8 & 3;
    int off = (h8 < 4) ? 0 : 32;
    double acc = 0.0;
    #pragma unroll
    for (int c = 0; c < 32; ++c)
        acc += bf2d(W[k * CIN + head * 32 + c]) * bf2d(att[head * 64 + off + c]);
    V[t] = acc;
}

// ---------------------------------------------------------------------------
// s-tables: sj4[n] = s_j heads (float4), si4[n] = s_i heads (float4)
__global__ __launch_bounds__(256) void k_s(const u16* __restrict__ x,
                                           const double* __restrict__ V,
                                           float4* __restrict__ sj4,
                                           float4* __restrict__ si4, int n_nodes) {
    __shared__ double Vl[1024];
    for (int i = threadIdx.x; i < 1024; i += 256) Vl[i] = V[i];
    __syncthreads();
    int n = blockIdx.x * blockDim.x + threadIdx.x;
    if (n >= n_nodes) return;
    const uint4* row = (const uint4*)(x + (size_t)n * CIN);
    double acc[8];
    #pragma unroll
    for (int h = 0; h < 8; ++h) acc[h] = 0.0;
    #pragma unroll
    for (int q = 0; q < 16; ++q) {
        uint4 v = row[q];
        u32 w[4] = { v.x, v.y, v.z, v.w };
        #pragma unroll
        for (int j = 0; j < 4; ++j) {
            double x0 = bf2d((u16)(w[j] & 0xFFFFu));
            double x1 = bf2d((u16)(w[j] >> 16));
            int k0 = q * 8 + j * 2;
            #pragma unroll
            for (int h = 0; h < 8; ++h) acc[h] += x0 * Vl[k0 * 8 + h];
            #pragma unroll
            for (int h = 0; h < 8; ++h) acc[h] += x1 * Vl[(k0 + 1) * 8 + h];
        }
    }
    float4 a, b;
    a.x = (float)acc[0]; a.y = (float)acc[1]; a.z = (float)acc[2]; a.w = (float)acc[3];
    b.x = (float)acc[4]; b.y = (float)acc[5]; b.z = (float)acc[6]; b.w = (float)acc[7];
    sj4[n] = a;
    si4[n] = b;
}

// ---------------------------------------------------------------------------
// Single fused edge pass: packed key = (mono32(alpha) << 32) | ~e.
// atomicMax -> max alpha, tie -> min edge id. Per-XCD private tables keep the
// atomic cache lines resident in the local L2 (no cross-XCD ping-pong).
__global__ __launch_bounds__(256) void k_edge(const int* __restrict__ ei,
                                              const float4* __restrict__ sj4,
                                              const float4* __restrict__ si4,
                                              u64* __restrict__ seg8,
                                              int n_edges, int n4, u32 pmask) {
    int e = blockIdx.x * blockDim.x + threadIdx.x;
    if (e >= n_edges) return;
    int src = ei[e], dst = ei[n_edges + e];
    float4 sj = sj4[src];
    float4 si = si4[dst];
    u64 lo = (u64)(u32)(~(u32)e);
    u64* seg = seg8 + (size_t)(xcd_id() & pmask) * (size_t)n4 + (size_t)src * 4;
    atomicMax(&seg[0], ((u64)mono32(sj.x + si.x) << 32) | lo);
    atomicMax(&seg[1], ((u64)mono32(sj.y + si.y) << 32) | lo);
    atomicMax(&seg[2], ((u64)mono32(sj.z + si.z) << 32) | lo);
    atomicMax(&seg[3], ((u64)mono32(sj.w + si.w) << 32) | lo);
}

// ---------------------------------------------------------------------------
// Fold the P per-XCD copies; decode winning edge; set node_mask[dst].
__global__ void k_select(const int* __restrict__ ei, const u64* __restrict__ seg8,
                         int* __restrict__ nm, int n4, int n_copies, int n_edges) {
    int t = blockIdx.x * blockDim.x + threadIdx.x;
    if (t >= n4) return;
    u64 m = 0;
    for (int p = 0; p < n_copies; ++p) {
        u64 v = seg8[(size_t)p * n4 + t];
        m = (v > m) ? v : m;
    }
    if (m) {
        int e = (int)(~(u32)m);
        nm[ei[n_edges + e]] = 1;     // race-benign: all writers store 1
    }
}

// ---------------------------------------------------------------------------
// edge_keep[e] = nm[src] & nm[dst], f32 1.0/0.0, 4 edges/thread
__global__ void k_edgekeep(const int* __restrict__ ei, const int* __restrict__ nm,
                           float4* __restrict__ out_ek, int n_edges) {
    int t = blockIdx.x * blockDim.x + threadIdx.x;
    int e0 = 4 * t;
    if (e0 >= n_edges) return;
    float4 v;
    v.x = (nm[ei[e0 + 0]] & nm[ei[n_edges + e0 + 0]]) ? 1.0f : 0.0f;
    v.y = (nm[ei[e0 + 1]] & nm[ei[n_edges + e0 + 1]]) ? 1.0f : 0.0f;
    v.z = (nm[ei[e0 + 2]] & nm[ei[n_edges + e0 + 2]]) ? 1.0f : 0.0f;
    v.w = (nm[ei[e0 + 3]] & nm[ei[n_edges + e0 + 3]]) ? 1.0f : 0.0f;
    out_ek[t] = v;
}

// ---------------------------------------------------------------------------
// node_mask f32 out + batch_slices f32 out
__global__ void k_nm_out(const int* __restrict__ nm, const int* __restrict__ slices,
                         float* __restrict__ out, int n_nodes, int nm_off, int sl_off) {
    int n = blockIdx.x * blockDim.x + threadIdx.x;
    if (n < n_nodes) out[nm_off + n] = nm[n] ? 1.0f : 0.0f;
    if (n < 2) out[sl_off + n] = (float)slices[n];   // 0 and 100000, exact in f32
}

// ---------------------------------------------------------------------------
extern "C" void kernel_launch(void* const* d_in, const int* in_sizes, int n_in,
                              void* d_out, int out_size, void* d_ws, size_t ws_size,
                              hipStream_t stream) {
    // Bind inputs by UNIQUE flat size (permutation-proof):
    const u16* x = nullptr; const int* ei = nullptr; const int* sl = nullptr;
    const u16* W = nullptr; const u16* att = nullptr;
    for (int i = 0; i < n_in; ++i) {
        switch (in_sizes[i]) {
            case NN * CIN:   x   = (const u16*)d_in[i]; break;
            case 2 * EE:     ei  = (const int*)d_in[i]; break;
            case 2:          sl  = (const int*)d_in[i]; break;
            case CIN * CIN:  W   = (const u16*)d_in[i]; break;
            case 256:        att = (const u16*)d_in[i]; break;
            default: break;
        }
    }
    if (!x || !ei || !sl || !W || !att) return;

    float* out = (float*)d_out;             // f32 concat, return order
    const int N = NN;
    const int E = EE;
    const int N4 = N * 4;

    // output layout (f32): [x_out N*128][edge_keep E][node_mask N][slices 2]
    const int ek_off = N * CIN;
    const int nm_off = ek_off + E;
    const int sl_off = nm_off + N;

    // workspace layout (16B-aligned):
    //   V 8 KB | sj4 N*16 | si4 N*16 | nm N*4 | seg8 P*N*32
    char* ws = (char*)d_ws;
    double* V   = (double*)(ws);
    float4* sj4 = (float4*)(ws + 8192);
    float4* si4 = (float4*)(ws + 8192 + (size_t)N * 16);
    int*    nm  = (int*)   (ws + 8192 + (size_t)N * 32);
    u64*  seg8  = (u64*)   (ws + 8192 + (size_t)N * 32 + (size_t)N * 4);

    // P per-XCD table copies if workspace allows (needs ~29.2 MB for P=8)
    size_t base = 8192 + (size_t)N * 36;
    int P = (ws_size >= base + 8ull * N4 * 8) ? 8 : 1;
    u32 pmask = (u32)(P - 1);

    const int n_xout16 = N * CIN / 4;        // uint4 count, f32 x_out region
    const int n_seg16  = P * N4 / 2;         // uint4 count, seg tables

    k_init<<<2048, 256, 0, stream>>>((uint4*)out, n_xout16, (uint4*)seg8, n_seg16, nm, N);
    k_prep_v<<<4, 256, 0, stream>>>(W, att, V);
    k_s<<<(N + 255) / 256, 256, 0, stream>>>(x, V, sj4, si4, N);
    k_edge<<<(E + 255) / 256, 256, 0, stream>>>(ei, sj4, si4, seg8, E, N4, pmask);
    k_select<<<(N4 + 255) / 256, 256, 0, stream>>>(ei, seg8, nm, N4, P, E);
    k_edgekeep<<<(E / 4 + 255) / 256, 256, 0, stream>>>(ei, nm, (float4*)(out + ek_off), E);
    k_nm_out<<<(N + 255) / 256, 256, 0, stream>>>(nm, sl, out, N, nm_off, sl_off);
}

// Round 5
// 307.661 us; speedup vs baseline: 2.1978x; 1.3359x over previous
//
#include <hip/hip_runtime.h>
#include <stdint.h>

typedef unsigned long long u64;
typedef unsigned int u32;
typedef unsigned short u16;

// Fixed problem shape (N=100000, E=1600000, C_IN=C_OUT=128, NHEADS=4)
#define CIN 128
#define NN 100000
#define EE 1600000

__device__ __forceinline__ double bf2d(u16 v) {
    union { u32 u; float f; } cv;
    cv.u = ((u32)v) << 16;           // bf16 -> f32 upcast is a shift (exact)
    return (double)cv.f;             // f32 -> f64 exact
}

// Monotonic map: f32 -> u32 preserving total order (for packed atomicMax key)
__device__ __forceinline__ u32 mono32(float f) {
    u32 u = __float_as_uint(f);
    return ((int)u >= 0) ? (u | 0x80000000u) : ~u;
}

// Hardware XCD id (0..7 on MI355X) — locality hint AND the correctness basis
// for workgroup-scope atomics: all atomics to table copy p come from XCD p,
// so they all execute at that XCD's TCC (one serialization point per line).
__device__ __forceinline__ u32 xcd_id() {
    u32 x;
    asm volatile("s_getreg_b32 %0, hwreg(HW_REG_XCC_ID)" : "=s"(x));
    return x & 7u;
}

// ---------------------------------------------------------------------------
// Init: zero x_out region of d_out (f32), zero seg tables (P copies), nm=0
__global__ void k_init(uint4* __restrict__ xout16, int n_xout16,
                       uint4* __restrict__ seg16, int n_seg16,
                       int* __restrict__ nm, int n_nodes) {
    int stride = gridDim.x * blockDim.x;
    int tid = blockIdx.x * blockDim.x + threadIdx.x;
    uint4 z; z.x = 0; z.y = 0; z.z = 0; z.w = 0;
    for (int i = tid; i < n_xout16; i += stride) xout16[i] = z;
    for (int i = tid; i < n_seg16; i += stride) seg16[i] = z;
    for (int i = tid; i < n_nodes; i += stride) nm[i] = 0;
}

// ---------------------------------------------------------------------------
// s-tables: sj4[n] = s_j heads (float4), si4[n] = s_i heads (float4).
// Each block computes the 1024-entry V table (W ⊗ att, f64 exact) into its own
// LDS — 128 f64 FMAs/thread, removes the separate k_prep_v kernel + global V.
__global__ __launch_bounds__(256) void k_s(const u16* __restrict__ x,
                                           const u16* __restrict__ W,
                                           const u16* __restrict__ att,
                                           float4* __restrict__ sj4,
                                           float4* __restrict__ si4, int n_nodes) {
    __shared__ double Vl[1024];
    for (int slot = threadIdx.x; slot < 1024; slot += 256) {
        int k = slot >> 3, h8 = slot & 7;
        int head = h8 & 3;
        int off = (h8 < 4) ? 0 : 32;
        double acc = 0.0;
        #pragma unroll
        for (int c = 0; c < 32; ++c)
            acc += bf2d(W[k * CIN + head * 32 + c]) * bf2d(att[head * 64 + off + c]);
        Vl[slot] = acc;
    }
    __syncthreads();
    int n = blockIdx.x * blockDim.x + threadIdx.x;
    if (n >= n_nodes) return;
    const uint4* row = (const uint4*)(x + (size_t)n * CIN);
    double acc[8];
    #pragma unroll
    for (int h = 0; h < 8; ++h) acc[h] = 0.0;
    #pragma unroll
    for (int q = 0; q < 16; ++q) {
        uint4 v = row[q];
        u32 w[4] = { v.x, v.y, v.z, v.w };
        #pragma unroll
        for (int j = 0; j < 4; ++j) {
            double x0 = bf2d((u16)(w[j] & 0xFFFFu));
            double x1 = bf2d((u16)(w[j] >> 16));
            int k0 = q * 8 + j * 2;
            #pragma unroll
            for (int h = 0; h < 8; ++h) acc[h] += x0 * Vl[k0 * 8 + h];
            #pragma unroll
            for (int h = 0; h < 8; ++h) acc[h] += x1 * Vl[(k0 + 1) * 8 + h];
        }
    }
    float4 a, b;
    a.x = (float)acc[0]; a.y = (float)acc[1]; a.z = (float)acc[2]; a.w = (float)acc[3];
    b.x = (float)acc[4]; b.y = (float)acc[5]; b.z = (float)acc[6]; b.w = (float)acc[7];
    sj4[n] = a;
    si4[n] = b;
}

// ---------------------------------------------------------------------------
// Single fused edge pass: packed key = (mono32(alpha) << 32) | ~e.
// max alpha, tie -> min edge id.
//  * test-then-atomic: slot values grow monotonically; stale test reads are
//    only ever smaller -> at worst an unnecessary atomic (correct).
//  * workgroup-scope atomicMax on XCD-private tables -> executes in the local
//    TCC (no memory-side round trip); one XCD per copy keeps it atomic.
__global__ __launch_bounds__(256) void k_edge(const int* __restrict__ ei,
                                              const float4* __restrict__ sj4,
                                              const float4* __restrict__ si4,
                                              u64* __restrict__ seg8,
                                              int n_edges, int n4, u32 pmask) {
    int e = blockIdx.x * blockDim.x + threadIdx.x;
    if (e >= n_edges) return;
    int src = ei[e], dst = ei[n_edges + e];
    float4 sj = sj4[src];
    float4 si = si4[dst];
    u64 lo = (u64)(u32)(~(u32)e);
    u64* seg = seg8 + (size_t)(xcd_id() & pmask) * (size_t)n4 + (size_t)src * 4;
    u64 c0 = seg[0], c1 = seg[1], c2 = seg[2], c3 = seg[3];
    u64 k0 = ((u64)mono32(sj.x + si.x) << 32) | lo;
    u64 k1 = ((u64)mono32(sj.y + si.y) << 32) | lo;
    u64 k2 = ((u64)mono32(sj.z + si.z) << 32) | lo;
    u64 k3 = ((u64)mono32(sj.w + si.w) << 32) | lo;
    if (k0 > c0) __hip_atomic_fetch_max(&seg[0], k0, __ATOMIC_RELAXED, __HIP_MEMORY_SCOPE_WORKGROUP);
    if (k1 > c1) __hip_atomic_fetch_max(&seg[1], k1, __ATOMIC_RELAXED, __HIP_MEMORY_SCOPE_WORKGROUP);
    if (k2 > c2) __hip_atomic_fetch_max(&seg[2], k2, __ATOMIC_RELAXED, __HIP_MEMORY_SCOPE_WORKGROUP);
    if (k3 > c3) __hip_atomic_fetch_max(&seg[3], k3, __ATOMIC_RELAXED, __HIP_MEMORY_SCOPE_WORKGROUP);
}

// ---------------------------------------------------------------------------
// Fold the P per-XCD copies; decode winning edge; set node_mask[dst].
__global__ void k_select(const int* __restrict__ ei, const u64* __restrict__ seg8,
                         int* __restrict__ nm, int n4, int n_copies, int n_edges) {
    int t = blockIdx.x * blockDim.x + threadIdx.x;
    if (t >= n4) return;
    u64 m = 0;
    for (int p = 0; p < n_copies; ++p) {
        u64 v = seg8[(size_t)p * n4 + t];
        m = (v > m) ? v : m;
    }
    if (m) {
        int e = (int)(~(u32)m);
        nm[ei[n_edges + e]] = 1;     // race-benign: all writers store 1
    }
}

// ---------------------------------------------------------------------------
// Fused epilogue: edge_keep (4 edges/thread, float4 stores) + node_mask f32 +
// batch_slices f32.
__global__ void k_final(const int* __restrict__ ei, const int* __restrict__ nm,
                        const int* __restrict__ slices, float* __restrict__ out,
                        int n_edges, int n_nodes, int ek_off, int nm_off, int sl_off) {
    int t = blockIdx.x * blockDim.x + threadIdx.x;
    int e0 = 4 * t;
    if (e0 < n_edges) {
        float4 v;
        v.x = (nm[ei[e0 + 0]] & nm[ei[n_edges + e0 + 0]]) ? 1.0f : 0.0f;
        v.y = (nm[ei[e0 + 1]] & nm[ei[n_edges + e0 + 1]]) ? 1.0f : 0.0f;
        v.z = (nm[ei[e0 + 2]] & nm[ei[n_edges + e0 + 2]]) ? 1.0f : 0.0f;
        v.w = (nm[ei[e0 + 3]] & nm[ei[n_edges + e0 + 3]]) ? 1.0f : 0.0f;
        ((float4*)(out + ek_off))[t] = v;
    }
    if (t < n_nodes) out[nm_off + t] = nm[t] ? 1.0f : 0.0f;
    if (t < 2) out[sl_off + t] = (float)slices[t];   // 0 and 100000, exact in f32
}

// ---------------------------------------------------------------------------
extern "C" void kernel_launch(void* const* d_in, const int* in_sizes, int n_in,
                              void* d_out, int out_size, void* d_ws, size_t ws_size,
                              hipStream_t stream) {
    // Bind inputs by UNIQUE flat size (permutation-proof):
    const u16* x = nullptr; const int* ei = nullptr; const int* sl = nullptr;
    const u16* W = nullptr; const u16* att = nullptr;
    for (int i = 0; i < n_in; ++i) {
        switch (in_sizes[i]) {
            case NN * CIN:   x   = (const u16*)d_in[i]; break;
            case 2 * EE:     ei  = (const int*)d_in[i]; break;
            case 2:          sl  = (const int*)d_in[i]; break;
            case CIN * CIN:  W   = (const u16*)d_in[i]; break;
            case 256:        att = (const u16*)d_in[i]; break;
            default: break;
        }
    }
    if (!x || !ei || !sl || !W || !att) return;

    float* out = (float*)d_out;             // f32 concat, return order
    const int N = NN;
    const int E = EE;
    const int N4 = N * 4;

    // output layout (f32): [x_out N*128][edge_keep E][node_mask N][slices 2]
    const int ek_off = N * CIN;
    const int nm_off = ek_off + E;
    const int sl_off = nm_off + N;

    // workspace layout (16B-aligned): sj4 N*16 | si4 N*16 | nm N*4 | seg8 P*N4*8
    char* ws = (char*)d_ws;
    float4* sj4 = (float4*)(ws);
    float4* si4 = (float4*)(ws + (size_t)N * 16);
    int*    nm  = (int*)   (ws + (size_t)N * 32);
    u64*  seg8  = (u64*)   (ws + (size_t)N * 36);

    size_t base = (size_t)N * 36;
    int P = (ws_size >= base + 8ull * N4 * 8) ? 8 : 1;
    u32 pmask = (u32)(P - 1);

    const int n_xout16 = N * CIN / 4;        // uint4 count, f32 x_out region
    const int n_seg16  = P * N4 / 2;         // uint4 count, seg tables

    k_init<<<2048, 256, 0, stream>>>((uint4*)out, n_xout16, (uint4*)seg8, n_seg16, nm, N);
    k_s<<<(N + 255) / 256, 256, 0, stream>>>(x, W, att, sj4, si4, N);
    k_edge<<<(E + 255) / 256, 256, 0, stream>>>(ei, sj4, si4, seg8, E, N4, pmask);
    k_select<<<(N4 + 255) / 256, 256, 0, stream>>>(ei, seg8, nm, N4, P, E);
    k_final<<<(E / 4 + 255) / 256, 256, 0, stream>>>(ei, nm, sl, out, E, N, ek_off, nm_off, sl_off);
}

// Round 7
// 300.151 us; speedup vs baseline: 2.2528x; 1.0250x over previous
//
#include <hip/hip_runtime.h>
#include <stdint.h>

typedef unsigned long long u64;
typedef unsigned int u32;
typedef unsigned short u16;
typedef u32 u32x4 __attribute__((ext_vector_type(4)));    // native clang vectors:
typedef float f32x4 __attribute__((ext_vector_type(4)));  // accepted by nontemporal builtins

// Fixed problem shape (N=100000, E=1600000, C_IN=C_OUT=128, NHEADS=4)
#define CIN 128
#define NN 100000
#define EE 1600000

__device__ __forceinline__ double bf2d(u16 v) {
    union { u32 u; float f; } cv;
    cv.u = ((u32)v) << 16;
    return (double)cv.f;
}

__device__ __forceinline__ float bf2f(u16 v) {
    union { u32 u; float f; } cv;
    cv.u = ((u32)v) << 16;
    return cv.f;
}

__device__ __forceinline__ u16 f2bf(float f) {      // RNE f32 -> bf16
    u32 b = __float_as_uint(f);
    return (u16)((b + 0x7FFFu + ((b >> 16) & 1u)) >> 16);
}

// Monotonic map: f32 -> u32 preserving total order (for packed atomicMax key)
__device__ __forceinline__ u32 mono32(float f) {
    u32 u = __float_as_uint(f);
    return ((int)u >= 0) ? (u | 0x80000000u) : ~u;
}

// Hardware XCD id (0..7 on MI355X). All atomics to table copy p come from
// XCD p only, so workgroup-scope (L2-local) RMWs are race-free per line.
__device__ __forceinline__ u32 xcd_id() {
    u32 x;
    asm volatile("s_getreg_b32 %0, hwreg(HW_REG_XCC_ID)" : "=s"(x));
    return x & 7u;
}

// ---------------------------------------------------------------------------
// k_s: (a) grid-stride zero of x_out region (nontemporal, 51.2 MB), seg
// tables and nm; (b) V table (W ⊗ att, f64 exact) in LDS; (c) s-tables as
// bf16x4 per node: sjb[n] (heads j), sib[n] (heads i) — 8 B each.
__global__ __launch_bounds__(256) void k_s(const u16* __restrict__ x,
                                           const u16* __restrict__ W,
                                           const u16* __restrict__ att,
                                           ushort4* __restrict__ sjb,
                                           ushort4* __restrict__ sib,
                                           u32x4* __restrict__ xout16, int n_xout16,
                                           u32x4* __restrict__ seg16, int n_seg16,
                                           int* __restrict__ nm, int n_nodes) {
    // ---- zero fill (independent of compute below) ----
    int stride = gridDim.x * blockDim.x;
    int tid = blockIdx.x * blockDim.x + threadIdx.x;
    u32x4 z = { 0, 0, 0, 0 };
    for (int i = tid; i < n_xout16; i += stride) __builtin_nontemporal_store(z, &xout16[i]);
    for (int i = tid; i < n_seg16; i += stride) seg16[i] = z;
    for (int i = tid; i < n_nodes; i += stride) nm[i] = 0;

    // ---- V table in LDS ----
    __shared__ double Vl[1024];
    for (int slot = threadIdx.x; slot < 1024; slot += 256) {
        int k = slot >> 3, h8 = slot & 7;
        int head = h8 & 3;
        int off = (h8 < 4) ? 0 : 32;
        double acc = 0.0;
        #pragma unroll
        for (int c = 0; c < 32; ++c)
            acc += bf2d(W[k * CIN + head * 32 + c]) * bf2d(att[head * 64 + off + c]);
        Vl[slot] = acc;
    }
    __syncthreads();

    int n = blockIdx.x * blockDim.x + threadIdx.x;
    if (n >= n_nodes) return;
    const uint4* row = (const uint4*)(x + (size_t)n * CIN);
    double acc[8];
    #pragma unroll
    for (int h = 0; h < 8; ++h) acc[h] = 0.0;
    #pragma unroll
    for (int q = 0; q < 16; ++q) {
        uint4 v = row[q];
        u32 w[4] = { v.x, v.y, v.z, v.w };
        #pragma unroll
        for (int j = 0; j < 4; ++j) {
            double x0 = bf2d((u16)(w[j] & 0xFFFFu));
            double x1 = bf2d((u16)(w[j] >> 16));
            int k0 = q * 8 + j * 2;
            #pragma unroll
            for (int h = 0; h < 8; ++h) acc[h] += x0 * Vl[k0 * 8 + h];
            #pragma unroll
            for (int h = 0; h < 8; ++h) acc[h] += x1 * Vl[(k0 + 1) * 8 + h];
        }
    }
    ushort4 a, b;
    a.x = f2bf((float)acc[0]); a.y = f2bf((float)acc[1]);
    a.z = f2bf((float)acc[2]); a.w = f2bf((float)acc[3]);
    b.x = f2bf((float)acc[4]); b.y = f2bf((float)acc[5]);
    b.z = f2bf((float)acc[6]); b.w = f2bf((float)acc[7]);
    sjb[n] = a;
    sib[n] = b;
}

// ---------------------------------------------------------------------------
// Fused edge pass, 4 edges/thread. key = (mono32(alpha) << 32) | ~e.
// test-then-atomic + workgroup-scope atomicMax on XCD-private tables.
__global__ __launch_bounds__(256) void k_edge(const int* __restrict__ ei,
                                              const ushort4* __restrict__ sjb,
                                              const ushort4* __restrict__ sib,
                                              u64* __restrict__ seg8,
                                              int n_edges, int n4, u32 pmask) {
    int t = blockIdx.x * blockDim.x + threadIdx.x;
    int e0 = 4 * t;
    if (e0 >= n_edges) return;
    int4 srcs = ((const int4*)ei)[t];
    int4 dsts = ((const int4*)(ei + n_edges))[t];
    u64* base = seg8 + (size_t)(xcd_id() & pmask) * (size_t)n4;
    int sa[4] = { srcs.x, srcs.y, srcs.z, srcs.w };
    int da[4] = { dsts.x, dsts.y, dsts.z, dsts.w };
    #pragma unroll
    for (int i = 0; i < 4; ++i) {
        int e = e0 + i;
        ushort4 sj = sjb[sa[i]];
        ushort4 si = sib[da[i]];
        u64 lo = (u64)(u32)(~(u32)e);
        u64* seg = base + (size_t)sa[i] * 4;
        ulonglong2 c01 = *(const ulonglong2*)(seg);
        ulonglong2 c23 = *(const ulonglong2*)(seg + 2);
        u64 k0 = ((u64)mono32(bf2f(sj.x) + bf2f(si.x)) << 32) | lo;
        u64 k1 = ((u64)mono32(bf2f(sj.y) + bf2f(si.y)) << 32) | lo;
        u64 k2 = ((u64)mono32(bf2f(sj.z) + bf2f(si.z)) << 32) | lo;
        u64 k3 = ((u64)mono32(bf2f(sj.w) + bf2f(si.w)) << 32) | lo;
        if (k0 > c01.x) __hip_atomic_fetch_max(&seg[0], k0, __ATOMIC_RELAXED, __HIP_MEMORY_SCOPE_WORKGROUP);
        if (k1 > c01.y) __hip_atomic_fetch_max(&seg[1], k1, __ATOMIC_RELAXED, __HIP_MEMORY_SCOPE_WORKGROUP);
        if (k2 > c23.x) __hip_atomic_fetch_max(&seg[2], k2, __ATOMIC_RELAXED, __HIP_MEMORY_SCOPE_WORKGROUP);
        if (k3 > c23.y) __hip_atomic_fetch_max(&seg[3], k3, __ATOMIC_RELAXED, __HIP_MEMORY_SCOPE_WORKGROUP);
    }
}

// ---------------------------------------------------------------------------
// Fold the P per-XCD copies; decode winning edge; set node_mask[dst].
__global__ void k_select(const int* __restrict__ ei, const u64* __restrict__ seg8,
                         int* __restrict__ nm, int n4, int n_copies, int n_edges) {
    int t = blockIdx.x * blockDim.x + threadIdx.x;
    if (t >= n4) return;
    u64 m = 0;
    for (int p = 0; p < n_copies; ++p) {
        u64 v = seg8[(size_t)p * n4 + t];
        m = (v > m) ? v : m;
    }
    if (m) {
        int e = (int)(~(u32)m);
        nm[ei[n_edges + e]] = 1;     // race-benign: all writers store 1
    }
}

// ---------------------------------------------------------------------------
// Fused epilogue: edge_keep (4 edges/thread, nontemporal float4) + node_mask
// f32 + batch_slices f32.
__global__ void k_final(const int* __restrict__ ei, const int* __restrict__ nm,
                        const int* __restrict__ slices, float* __restrict__ out,
                        int n_edges, int n_nodes, int ek_off, int nm_off, int sl_off) {
    int t = blockIdx.x * blockDim.x + threadIdx.x;
    int e0 = 4 * t;
    if (e0 < n_edges) {
        int4 srcs = ((const int4*)ei)[t];
        int4 dsts = ((const int4*)(ei + n_edges))[t];
        f32x4 v;
        v.x = (nm[srcs.x] & nm[dsts.x]) ? 1.0f : 0.0f;
        v.y = (nm[srcs.y] & nm[dsts.y]) ? 1.0f : 0.0f;
        v.z = (nm[srcs.z] & nm[dsts.z]) ? 1.0f : 0.0f;
        v.w = (nm[srcs.w] & nm[dsts.w]) ? 1.0f : 0.0f;
        __builtin_nontemporal_store(v, &((f32x4*)(out + ek_off))[t]);
    }
    if (t < n_nodes) out[nm_off + t] = nm[t] ? 1.0f : 0.0f;
    if (t < 2) out[sl_off + t] = (float)slices[t];   // 0 and 100000, exact
}

// ---------------------------------------------------------------------------
extern "C" void kernel_launch(void* const* d_in, const int* in_sizes, int n_in,
                              void* d_out, int out_size, void* d_ws, size_t ws_size,
                              hipStream_t stream) {
    // Bind inputs by UNIQUE flat size (permutation-proof):
    const u16* x = nullptr; const int* ei = nullptr; const int* sl = nullptr;
    const u16* W = nullptr; const u16* att = nullptr;
    for (int i = 0; i < n_in; ++i) {
        switch (in_sizes[i]) {
            case NN * CIN:   x   = (const u16*)d_in[i]; break;
            case 2 * EE:     ei  = (const int*)d_in[i]; break;
            case 2:          sl  = (const int*)d_in[i]; break;
            case CIN * CIN:  W   = (const u16*)d_in[i]; break;
            case 256:        att = (const u16*)d_in[i]; break;
            default: break;
        }
    }
    if (!x || !ei || !sl || !W || !att) return;

    float* out = (float*)d_out;             // f32 concat, return order
    const int N = NN;
    const int E = EE;
    const int N4 = N * 4;

    // output layout (f32): [x_out N*128][edge_keep E][node_mask N][slices 2]
    const int ek_off = N * CIN;
    const int nm_off = ek_off + E;
    const int sl_off = nm_off + N;

    // workspace (all offsets 32B-aligned):
    //   sjb N*8 | sib N*8 | nm N*4 + pad | seg8 P*N4*8
    char* ws = (char*)d_ws;
    ushort4* sjb = (ushort4*)(ws);
    ushort4* sib = (ushort4*)(ws + (size_t)N * 8);
    int*     nm  = (int*)    (ws + (size_t)N * 16);
    u64*   seg8  = (u64*)    (ws + (size_t)N * 16 + (size_t)N * 4 + 32);

    size_t base = (size_t)N * 20 + 32;
    int P = (ws_size >= base + 8ull * N4 * 8) ? 8 : 1;
    u32 pmask = (u32)(P - 1);

    const int n_xout16 = N * CIN / 4;        // u32x4 count, f32 x_out region
    const int n_seg16  = P * N4 / 2;         // u32x4 count, seg tables

    k_s<<<(N + 255) / 256, 256, 0, stream>>>(x, W, att, sjb, sib,
                                             (u32x4*)out, n_xout16,
                                             (u32x4*)seg8, n_seg16, nm, N);
    k_edge<<<(E / 4 + 255) / 256, 256, 0, stream>>>(ei, sjb, sib, seg8, E, N4, pmask);
    k_select<<<(N4 + 255) / 256, 256, 0, stream>>>(ei, seg8, nm, N4, P, E);
    k_final<<<(E / 4 + 255) / 256, 256, 0, stream>>>(ei, nm, sl, out, E, N, ek_off, nm_off, sl_off);
}